// Round 13
// baseline (314.886 us; speedup 1.0000x reference)
//
#include <hip/hip_runtime.h>
#include <math.h>

#define T_IN 2048
#define TP   2051   // T+3 conv output length
#define F    256
#define H    384
#define XTS  2112   // xpT row stride (33*64)
#define NTB  33     // k2 t-blocks of 64
#define NCS  257    // 8-t chunks (scan length)
#define NC3  257    // k3 chunks of 8

// SESSION LEDGER (best so far R7/R12: 140.7/142.1us):
//  R5/R6: fence+ticket epilogue = ~90us TCC storm. Never fence.
//  R2..R9 k2 variants all 42us: CU-level LDS-pipe total is occupancy-invariant;
//  4x2 micro-tile = 4.5:1 LDS:VALU -> 84K LDS-cyc/CU = 40us. THIS round: 8x8
//  micro-tile (64 FMA per 4 b128) -> 1.1:1, 198 blocks single-round, pred ~20us.

__device__ __forceinline__ float logsig(float z) {
    return (z >= 0.0f) ? -log1pf(__expf(-z)) : z - log1pf(__expf(z));
}

union F4 { float4 v; float f[4]; };

// ---------- D1: conv+transpose (0..512) + q/o GEMV (513..608) + zero (609) ----------
// Verified in R9 (passed, absmax 0.0). xpT is k-major [f][t] for k2 staging.
__global__ __launch_bounds__(256) void k1_front(const float* __restrict__ x,
        const float* __restrict__ cw, const float* __restrict__ cb,
        const float* __restrict__ Wq, const float* __restrict__ bq,
        const float* __restrict__ Wo, const float* __restrict__ bo,
        float* __restrict__ xp, float* __restrict__ xpT,
        float* __restrict__ q, float* __restrict__ o,
        float* __restrict__ zf) {
    int bid = blockIdx.x;
    int tid = threadIdx.x;
    if (bid < 513) {
        __shared__ float tr[4][257];
        int tl = tid >> 6;
        int f4 = tid & 63;
        int t = bid * 4 + tl;
        float4 acc = {0.f, 0.f, 0.f, 0.f};
        if (t < TP) {
            float w[4] = {cw[0], cw[1], cw[2], cw[3]};
            float b = cb[0];
            acc.x = b; acc.y = b; acc.z = b; acc.w = b;
            int i0 = t - 3;
            const float4* x4 = (const float4*)x;
            #pragma unroll
            for (int j = 0; j < 4; ++j) {
                int tt = i0 + j;
                if (tt >= 0 && tt < T_IN) {
                    float4 xv = x4[tt * 64 + f4];
                    acc.x = fmaf(w[j], xv.x, acc.x);
                    acc.y = fmaf(w[j], xv.y, acc.y);
                    acc.z = fmaf(w[j], xv.z, acc.z);
                    acc.w = fmaf(w[j], xv.w, acc.w);
                }
            }
            ((float4*)xp)[t * 64 + f4] = acc;
        }
        *(float4*)&tr[tl][f4 * 4] = acc;   // 0 for t>=TP
        __syncthreads();
        float4 v;
        v.x = tr[0][tid]; v.y = tr[1][tid]; v.z = tr[2][tid]; v.w = tr[3][tid];
        *(float4*)&xpT[tid * XTS + bid * 4] = v;
    } else if (bid < 609) {
        int lane = tid & 63;
        int row = (bid - 513) * 4 + (tid >> 6);
        float w0 = cw[0], b = cb[0];
        float4 xr = ((const float4*)x)[2047 * 64 + lane];
        float4 xv;
        xv.x = fmaf(w0, xr.x, b);
        xv.y = fmaf(w0, xr.y, b);
        xv.z = fmaf(w0, xr.z, b);
        xv.w = fmaf(w0, xr.w, b);
        float4 q4 = *(const float4*)&Wq[row * 256 + lane * 4];
        float4 o4 = *(const float4*)&Wo[row * 256 + lane * 4];
        float aq = fmaf(xv.x, q4.x, fmaf(xv.y, q4.y, fmaf(xv.z, q4.z, xv.w * q4.w)));
        float ao = fmaf(xv.x, o4.x, fmaf(xv.y, o4.y, fmaf(xv.z, o4.z, xv.w * o4.w)));
        #pragma unroll
        for (int off = 32; off; off >>= 1) {
            aq += __shfl_down(aq, off, 64);
            ao += __shfl_down(ao, off, 64);
        }
        if (lane == 0) {
            q[row] = aq + bq[row];
            o[row] = 1.0f / (1.0f + __expf(-(ao + bo[row])));
        }
    } else {
        for (int i = tid; i < 272; i += 256) zf[i] = 0.0f;
        // zero xpT pad columns 2052..2111
        for (int i = tid; i < 256 * 60; i += 256) {
            int r = i / 60, c = 2052 + i % 60;
            xpT[r * XTS + c] = 0.0f;
        }
    }
}

// ---------- D2: 64t x 64b x 3mat, 192 thr (wave=mat), 8t x 8b micro-tile ----------
// grid (33,6) = 198 blocks (<=1/CU, single round). Per kk per lane: 2 a-b128 +
// 2 w-b128 -> 64 FMA. LDS layouts [k][t] / [mat][k][b], rows 68 floats (272B,
// 16B-aligned; lane groups 2-way bank alias = free). Double-buffered, 1 barrier
// per 32k-tile (8 total). k-ascending fmaf chain == previous versions bit-exact.
__global__ __launch_bounds__(192) void k2_proj(
    const float* __restrict__ xpT,
    const float* __restrict__ Wk, const float* __restrict__ bk,
    const float* __restrict__ Wi, const float* __restrict__ bi,
    const float* __restrict__ Wf, const float* __restrict__ bf,
    float* __restrict__ zk, float* __restrict__ ai, float* __restrict__ lf,
    float* __restrict__ cs) {
    __shared__ float alds[2][32][68];      // [buf][k][t]
    __shared__ float wlds[2][3][32][68];   // [buf][mat][k][b]
    int tid = threadIdx.x;
    int wv = tid >> 6;            // wave = matrix (0:k 1:i 2:f)
    int lane = tid & 63;
    int tg = lane >> 3;           // t-octet 0..7
    int bg = lane & 7;            // b-octet 0..7
    int t0 = blockIdx.x * 64, b0 = blockIdx.y * 64;
    const float* __restrict__ bias = (wv == 0) ? bk : (wv == 1) ? bi : bf;

    float4 accA[8], accB[8];
    #pragma unroll
    for (int i = 0; i < 8; ++i) {
        accA[i].x = accA[i].y = accA[i].z = accA[i].w = 0.f;
        accB[i].x = accB[i].y = accB[i].z = accB[i].w = 0.f;
    }

    float4 awp[3], wwp[8];
    // prologue: load k-tile 0
    #pragma unroll
    for (int r = 0; r < 3; ++r) {
        int j = tid + r * 192;
        if (j < 512) {
            int k = j >> 4, t4 = (j & 15) * 4;
            awp[r] = *(const float4*)&xpT[k * XTS + t0 + t4];
        }
    }
    #pragma unroll
    for (int r = 0; r < 8; ++r) {
        int fl = tid + r * 192;
        int m = fl >> 9, rem = fl & 511;
        int b = rem >> 3, kq = (rem & 7) * 4;
        const float* Wm = (m == 0) ? Wk : (m == 1) ? Wi : Wf;
        wwp[r] = *(const float4*)&Wm[(b0 + b) * 256 + kq];
    }

    for (int it = 0; it < 8; ++it) {
        int buf = it & 1;
        #pragma unroll
        for (int r = 0; r < 3; ++r) {
            int j = tid + r * 192;
            if (j < 512) {
                int k = j >> 4, t4 = (j & 15) * 4;
                *(float4*)&alds[buf][k][t4] = awp[r];
            }
        }
        #pragma unroll
        for (int r = 0; r < 8; ++r) {
            int fl = tid + r * 192;
            int m = fl >> 9, rem = fl & 511;
            int b = rem >> 3, kq = (rem & 7) * 4;
            F4 u; u.v = wwp[r];
            #pragma unroll
            for (int j = 0; j < 4; ++j)
                wlds[buf][m][kq + j][b] = u.f[j];
        }
        __syncthreads();
        if (it < 7) {
            int k0 = (it + 1) * 32;
            #pragma unroll
            for (int r = 0; r < 3; ++r) {
                int j = tid + r * 192;
                if (j < 512) {
                    int k = j >> 4, t4 = (j & 15) * 4;
                    awp[r] = *(const float4*)&xpT[(k0 + k) * XTS + t0 + t4];
                }
            }
            #pragma unroll
            for (int r = 0; r < 8; ++r) {
                int fl = tid + r * 192;
                int m = fl >> 9, rem = fl & 511;
                int b = rem >> 3, kq = (rem & 7) * 4;
                const float* Wm = (m == 0) ? Wk : (m == 1) ? Wi : Wf;
                wwp[r] = *(const float4*)&Wm[(b0 + b) * 256 + k0 + kq];
            }
        }
        #pragma unroll 4
        for (int kk = 0; kk < 32; ++kk) {
            F4 A0, A1, W0, W1;
            A0.v = *(const float4*)&alds[buf][kk][tg * 8];
            A1.v = *(const float4*)&alds[buf][kk][tg * 8 + 4];
            W0.v = *(const float4*)&wlds[buf][wv][kk][bg * 8];
            W1.v = *(const float4*)&wlds[buf][wv][kk][bg * 8 + 4];
            #pragma unroll
            for (int i = 0; i < 8; ++i) {
                float av = (i < 4) ? A0.f[i] : A1.f[i - 4];
                accA[i].x = fmaf(av, W0.f[0], accA[i].x);
                accA[i].y = fmaf(av, W0.f[1], accA[i].y);
                accA[i].z = fmaf(av, W0.f[2], accA[i].z);
                accA[i].w = fmaf(av, W0.f[3], accA[i].w);
                accB[i].x = fmaf(av, W1.f[0], accB[i].x);
                accB[i].y = fmaf(av, W1.f[1], accB[i].y);
                accB[i].z = fmaf(av, W1.f[2], accB[i].z);
                accB[i].w = fmaf(av, W1.f[3], accB[i].w);
            }
        }
        __syncthreads();
    }
    // epilogue: per thread 8t x 8b of one matrix
    int bA = b0 + bg * 8;
    float4 b4a = *(const float4*)&bias[bA];
    float4 b4b = *(const float4*)&bias[bA + 4];
    if (wv == 0) {
        const float sc = 0.05103103630798287f;  // 1/sqrt(384)
        #pragma unroll
        for (int i = 0; i < 8; ++i) {
            int t = t0 + tg * 8 + i;
            if (t < TP) {
                float4 v0, v1;
                v0.x = (accA[i].x + b4a.x) * sc; v0.y = (accA[i].y + b4a.y) * sc;
                v0.z = (accA[i].z + b4a.z) * sc; v0.w = (accA[i].w + b4a.w) * sc;
                v1.x = (accB[i].x + b4b.x) * sc; v1.y = (accB[i].y + b4b.y) * sc;
                v1.z = (accB[i].z + b4b.z) * sc; v1.w = (accB[i].w + b4b.w) * sc;
                *(float4*)&zk[t * H + bA] = v0;
                *(float4*)&zk[t * H + bA + 4] = v1;
            }
        }
    } else if (wv == 1) {
        #pragma unroll
        for (int i = 0; i < 8; ++i) {
            int t = t0 + tg * 8 + i;
            if (t < TP) {
                float4 v0, v1;
                v0.x = accA[i].x + b4a.x; v0.y = accA[i].y + b4a.y;
                v0.z = accA[i].z + b4a.z; v0.w = accA[i].w + b4a.w;
                v1.x = accB[i].x + b4b.x; v1.y = accB[i].y + b4b.y;
                v1.z = accB[i].z + b4b.z; v1.w = accB[i].w + b4b.w;
                *(float4*)&ai[t * H + bA] = v0;
                *(float4*)&ai[t * H + bA + 4] = v1;
            }
        }
    } else {
        // lf + per-chunk sums. Thread's 8 t's == exactly chunk c = bx*8+tg.
        // cs order matches old: (t0..t3 sum) + (t4..t7 sum).
        float4 s0a = {0,0,0,0}, s0b = {0,0,0,0}, s1a = {0,0,0,0}, s1b = {0,0,0,0};
        #pragma unroll
        for (int i = 0; i < 8; ++i) {
            int t = t0 + tg * 8 + i;
            if (t < TP) {
                float4 l0, l1;
                l0.x = logsig(accA[i].x + b4a.x); l0.y = logsig(accA[i].y + b4a.y);
                l0.z = logsig(accA[i].z + b4a.z); l0.w = logsig(accA[i].w + b4a.w);
                l1.x = logsig(accB[i].x + b4b.x); l1.y = logsig(accB[i].y + b4b.y);
                l1.z = logsig(accB[i].z + b4b.z); l1.w = logsig(accB[i].w + b4b.w);
                *(float4*)&lf[t * H + bA] = l0;
                *(float4*)&lf[t * H + bA + 4] = l1;
                if (i < 4) {
                    s0a.x += l0.x; s0a.y += l0.y; s0a.z += l0.z; s0a.w += l0.w;
                    s0b.x += l1.x; s0b.y += l1.y; s0b.z += l1.z; s0b.w += l1.w;
                } else {
                    s1a.x += l0.x; s1a.y += l0.y; s1a.z += l0.z; s1a.w += l0.w;
                    s1b.x += l1.x; s1b.y += l1.y; s1b.z += l1.z; s1b.w += l1.w;
                }
            }
        }
        int c = blockIdx.x * 8 + tg;
        if (c < NCS) {
            float4 c0, c1;
            c0.x = s0a.x + s1a.x; c0.y = s0a.y + s1a.y;
            c0.z = s0a.z + s1a.z; c0.w = s0a.w + s1a.w;
            c1.x = s0b.x + s1b.x; c1.y = s0b.y + s1b.y;
            c1.z = s0b.z + s1b.z; c1.w = s0b.w + s1b.w;
            *(float4*)&cs[c * H + bA] = c0;
            *(float4*)&cs[c * H + bA + 4] = c1;
        }
    }
}

// ---------- D3: reverse exclusive scan over 257 chunk sums, grid 6x64 ----------
__global__ __launch_bounds__(64) void k3b_scan(const float* __restrict__ cs,
                                               float* __restrict__ co) {
    int b = blockIdx.x * 64 + threadIdx.x;
    float L = 0.0f;
    #pragma unroll 16
    for (int c = NCS - 1; c >= 0; --c) {
        co[c * H + b] = L;
        L += cs[c * H + b];
    }
}

// ---------- D4: fused w -> g -> atomic (z, G). grid NC3 x 384, chunk 8 t ----------
__global__ __launch_bounds__(384) void k3_fused(
    const float* __restrict__ ai, const float* __restrict__ lf,
    const float* __restrict__ zk, const float* __restrict__ co,
    const float* __restrict__ q, const float* __restrict__ xp,
    float* __restrict__ zf, float* __restrict__ Gf) {
    __shared__ float zred[6][256];
    __shared__ float gred[6];
    int tid = threadIdx.x;
    int w = tid >> 6, lane = tid & 63;
    int c = blockIdx.x, ts = c * 8;
    float co0 = co[c * H + tid];
    float qb = q[tid];
    float aiv[8], lfv[8], zkv[8];
    float4 xv[8];
    if (ts + 8 <= TP) {
        #pragma unroll
        for (int u = 0; u < 8; ++u) {
            int idx = (ts + u) * H + tid;
            aiv[u] = ai[idx]; lfv[u] = lf[idx]; zkv[u] = zk[idx];
            xv[u] = *(const float4*)&xp[(ts + u) * 256 + lane * 4];
        }
    } else {
        #pragma unroll
        for (int u = 0; u < 8; ++u) {
            if (ts + u < TP) {
                int idx = (ts + u) * H + tid;
                aiv[u] = ai[idx]; lfv[u] = lf[idx]; zkv[u] = zk[idx];
                xv[u] = *(const float4*)&xp[(ts + u) * 256 + lane * 4];
            } else {
                aiv[u] = -1e30f; lfv[u] = 0.f; zkv[u] = 0.f;
                xv[u].x = xv[u].y = xv[u].z = xv[u].w = 0.f;
            }
        }
    }
    float S = 0.f, gsum = 0.f;
    float z0 = 0.f, z1 = 0.f, z2 = 0.f, z3 = 0.f;
    #pragma unroll
    for (int u = 7; u >= 0; --u) {
        float wv = __expf(aiv[u] + co0 + S) * zkv[u] * qb;
        S += lfv[u];
        float s = wv;
        s += __shfl_xor(s, 1, 64);
        s += __shfl_xor(s, 2, 64);
        s += __shfl_xor(s, 4, 64);
        s += __shfl_xor(s, 8, 64);
        s += __shfl_xor(s, 16, 64);
        s += __shfl_xor(s, 32, 64);
        gsum += s;
        z0 = fmaf(s, xv[u].x, z0);
        z1 = fmaf(s, xv[u].y, z1);
        z2 = fmaf(s, xv[u].z, z2);
        z3 = fmaf(s, xv[u].w, z3);
    }
    zred[w][lane * 4 + 0] = z0;
    zred[w][lane * 4 + 1] = z1;
    zred[w][lane * 4 + 2] = z2;
    zred[w][lane * 4 + 3] = z3;
    if (lane == 0) gred[w] = gsum;
    __syncthreads();
    if (tid < 256) {
        float s = zred[0][tid] + zred[1][tid] + zred[2][tid]
                + zred[3][tid] + zred[4][tid] + zred[5][tid];
        atomicAdd(&zf[tid], s);
    }
    if (tid == 0)
        atomicAdd(Gf, gred[0] + gred[1] + gred[2] + gred[3] + gred[4] + gred[5]);
}

// ---------- D5: wave-per-row GEMV finalize, grid 96 ----------
__global__ __launch_bounds__(256) void k6_out(const float* __restrict__ zf,
        const float* __restrict__ Gf,
        const float* __restrict__ Wv, const float* __restrict__ bv,
        const float* __restrict__ o, float* __restrict__ out) {
    int tid = threadIdx.x;
    int lane = tid & 63;
    int row = blockIdx.x * 4 + (tid >> 6);
    float Gv = Gf[0];
    float4 zv = *(const float4*)&zf[lane * 4];
    float4 wv = *(const float4*)&Wv[row * 256 + lane * 4];
    float acc = fmaf(zv.x, wv.x, fmaf(zv.y, wv.y, fmaf(zv.z, wv.z, zv.w * wv.w)));
    #pragma unroll
    for (int off = 32; off; off >>= 1) acc += __shfl_down(acc, off, 64);
    if (lane == 0)
        out[row] = o[row] * (acc + bv[row] * Gv) / fmaxf(fabsf(Gv), 1.0f);
}

extern "C" void kernel_launch(void* const* d_in, const int* in_sizes, int n_in,
                              void* d_out, int out_size, void* d_ws, size_t ws_size,
                              hipStream_t stream) {
    const float* x  = (const float*)d_in[0];
    const float* Wq = (const float*)d_in[1];  const float* bq = (const float*)d_in[2];
    const float* Wk = (const float*)d_in[3];  const float* bk = (const float*)d_in[4];
    const float* Wv = (const float*)d_in[5];  const float* bv = (const float*)d_in[6];
    const float* Wi = (const float*)d_in[7];  const float* bi = (const float*)d_in[8];
    const float* Wf = (const float*)d_in[9];  const float* bf = (const float*)d_in[10];
    const float* Wo = (const float*)d_in[11]; const float* bo = (const float*)d_in[12];
    const float* cw = (const float*)d_in[13]; const float* cb = (const float*)d_in[14];
    float* out = (float*)d_out;

    float* ws = (float*)d_ws;
    float* xp  = ws;                       // TP*F
    float* zk  = xp  + TP * F;             // TP*H
    float* ai  = zk  + TP * H;             // TP*H
    float* lf  = ai  + TP * H;             // TP*H
    float* cs  = lf  + TP * H;             // NCS*H
    float* co  = cs  + NCS * H;            // NCS*H
    float* qv  = co  + NCS * H;            // H
    float* ov  = qv  + H;                  // H
    float* zf  = ov  + H;                  // 256 + Gf + pad (272 reserved)
    float* Gf  = zf  + F;                  // at zf+256
    float* xpT = zf  + 512;                // 256 x XTS transposed conv output

    k1_front<<<610, 256, 0, stream>>>(x, cw, cb, Wq, bq, Wo, bo, xp, xpT, qv, ov, zf);
    k2_proj<<<dim3(NTB, 6), 192, 0, stream>>>(xpT, Wk, bk, Wi, bi, Wf, bf, zk, ai, lf, cs);
    k3b_scan<<<6, 64, 0, stream>>>(cs, co);
    k3_fused<<<NC3, 384, 0, stream>>>(ai, lf, zk, co, qv, xp, zf, Gf);
    k6_out<<<96, 256, 0, stream>>>(zf, Gf, Wv, bv, ov, out);
}

// Round 14
// 141.338 us; speedup vs baseline: 2.2279x; 2.2279x over previous
//
#include <hip/hip_runtime.h>
#include <math.h>

#define T_IN 2048
#define TP   2051   // T+3 conv output length
#define F    256
#define H    384
#define BK   16     // k2 K-tile
#define BT2  32     // k2 t-tile
#define NT2  65     // ceil(TP/32) t-tiles in k2
#define NCS  257    // 8-t chunks (scan length)
#define NC3  257    // k3 chunks of 8

// SESSION LEDGER (best = this config: R7 140.7us, re-confirmed R12 142.1us):
//  R5/R6 212/228: fence+ticket epilogue = ~90us TCC storm. Never fence.
//  R7: fence removed + k1 fusion (BEST).
//  k2 rewrites all failed: R3 z-split 42us, R8 4x4 tile 42us, R9 scalar-W 45us,
//  R13 8x8 tile 210us (1 blk/CU, 3 waves, latency-bound, 912K bank conflicts).
//  Backend splits failed: R5 self-scan, R10 chunk-4 (+6us).
//  The 42us k2 plateau is a balance point: more intensity -> fewer blocks ->
//  latency-bound; more blocks -> LDS/issue-bound. Do not re-tile.

__device__ __forceinline__ float logsig(float z) {
    return (z >= 0.0f) ? -log1pf(__expf(-z)) : z - log1pf(__expf(z));
}

union F4 { float4 v; float f[4]; };

// ---------- D1: conv (blocks 0..512) + q/o GEMV (513..608) + zero (609) ----------
// qo path: xp[TP-1, f] = cb + cw[0]*x[2047, f] exactly (taps t>=2048 are out of
// range), so it needs no conv output -> safe to fuse in the same dispatch.
__global__ __launch_bounds__(256) void k1_front(const float* __restrict__ x,
        const float* __restrict__ cw, const float* __restrict__ cb,
        const float* __restrict__ Wq, const float* __restrict__ bq,
        const float* __restrict__ Wo, const float* __restrict__ bo,
        float* __restrict__ xp, float* __restrict__ q, float* __restrict__ o,
        float* __restrict__ zf) {
    int bid = blockIdx.x;
    int tid = threadIdx.x;
    if (bid < 513) {
        int t = bid * 4 + (tid >> 6);
        int f4 = tid & 63;
        if (t >= TP) return;
        float w[4] = {cw[0], cw[1], cw[2], cw[3]};
        float b = cb[0];
        float4 acc = {b, b, b, b};
        int i0 = t - 3;
        const float4* x4 = (const float4*)x;
        #pragma unroll
        for (int j = 0; j < 4; ++j) {
            int tt = i0 + j;
            if (tt >= 0 && tt < T_IN) {
                float4 xv = x4[tt * 64 + f4];
                acc.x = fmaf(w[j], xv.x, acc.x);
                acc.y = fmaf(w[j], xv.y, acc.y);
                acc.z = fmaf(w[j], xv.z, acc.z);
                acc.w = fmaf(w[j], xv.w, acc.w);
            }
        }
        ((float4*)xp)[t * 64 + f4] = acc;
    } else if (bid < 609) {
        int lane = tid & 63;
        int row = (bid - 513) * 4 + (tid >> 6);
        float w0 = cw[0], b = cb[0];
        float4 xr = ((const float4*)x)[2047 * 64 + lane];
        float4 xv;
        xv.x = fmaf(w0, xr.x, b);
        xv.y = fmaf(w0, xr.y, b);
        xv.z = fmaf(w0, xr.z, b);
        xv.w = fmaf(w0, xr.w, b);
        float4 q4 = *(const float4*)&Wq[row * 256 + lane * 4];
        float4 o4 = *(const float4*)&Wo[row * 256 + lane * 4];
        float aq = fmaf(xv.x, q4.x, fmaf(xv.y, q4.y, fmaf(xv.z, q4.z, xv.w * q4.w)));
        float ao = fmaf(xv.x, o4.x, fmaf(xv.y, o4.y, fmaf(xv.z, o4.z, xv.w * o4.w)));
        #pragma unroll
        for (int off = 32; off; off >>= 1) {
            aq += __shfl_down(aq, off, 64);
            ao += __shfl_down(ao, off, 64);
        }
        if (lane == 0) {
            q[row] = aq + bq[row];
            o[row] = 1.0f / (1.0f + __expf(-(ao + bo[row])));
        }
    } else {
        // zero zf (256) + Gf (at 256) + pad
        for (int i = tid; i < 272; i += 256) zf[i] = 0.0f;
    }
}

// ---------- D2: 32t x 64b x 1 matrix per block, grid (65,6,3) = 1170 blocks ----------
// FROZEN: the 42us balance point (see ledger).
__global__ __launch_bounds__(256) void k2_proj(
    const float* __restrict__ xp,
    const float* __restrict__ Wk, const float* __restrict__ bk,
    const float* __restrict__ Wi, const float* __restrict__ bi,
    const float* __restrict__ Wf, const float* __restrict__ bf,
    float* __restrict__ zk, float* __restrict__ ai, float* __restrict__ lf,
    float* __restrict__ cs) {
    __shared__ float alds[2][BT2][20];    // xp tile [t][k], pad 20 (float4-aligned)
    __shared__ float wlds[2][BK][66];     // W^T [k][b]
    __shared__ float csred[8][66];
    int tid = threadIdx.x;
    int mz = blockIdx.z;
    const float* __restrict__ W    = (mz == 0) ? Wk : (mz == 1) ? Wi : Wf;
    const float* __restrict__ bias = (mz == 0) ? bk : (mz == 1) ? bi : bf;
    int t0 = blockIdx.x * BT2, b0 = blockIdx.y * 64;
    int tx = tid & 31, ty = tid >> 5;
    float2 acc[4];
    #pragma unroll
    for (int u = 0; u < 4; ++u) { acc[u].x = 0.f; acc[u].y = 0.f; }

    int wrow = tid >> 2;          // 0..63 (W row within tile)
    int wk4 = (tid & 3) * 4;      // k quad
    int grow = (b0 + wrow) * 256 + wk4;
    int atq = tid >> 2;           // 0..31 (a row within tile, tid<128 only)
    int arow = (t0 + atq) * 256 + wk4;
    bool aval = (tid < 128) && (t0 + atq < TP);

    float4 aw = {0.f, 0.f, 0.f, 0.f};
    float4 ww;
    // prologue: load tile 0
    if (aval) aw = *(const float4*)&xp[arow];
    ww = *(const float4*)&W[grow];

    for (int i = 0; i < 16; ++i) {
        int buf = i & 1;
        if (tid < 128) *(float4*)&alds[buf][atq][wk4] = aw;
        {
            F4 wu; wu.v = ww;
            #pragma unroll
            for (int j = 0; j < 4; ++j)
                wlds[buf][wk4 + j][wrow] = wu.f[j];
        }
        __syncthreads();
        if (i < 15) {
            int k0 = (i + 1) * BK;
            if (aval) aw = *(const float4*)&xp[arow + k0];
            ww = *(const float4*)&W[grow + k0];
        }
        #pragma unroll
        for (int g = 0; g < 4; ++g) {
            F4 av0, av1, av2, av3;
            av0.v = *(const float4*)&alds[buf][4 * ty + 0][4 * g];
            av1.v = *(const float4*)&alds[buf][4 * ty + 1][4 * g];
            av2.v = *(const float4*)&alds[buf][4 * ty + 2][4 * g];
            av3.v = *(const float4*)&alds[buf][4 * ty + 3][4 * g];
            #pragma unroll
            for (int j = 0; j < 4; ++j) {
                float2 w0 = *(const float2*)&wlds[buf][4 * g + j][2 * tx];
                acc[0].x = fmaf(av0.f[j], w0.x, acc[0].x);
                acc[0].y = fmaf(av0.f[j], w0.y, acc[0].y);
                acc[1].x = fmaf(av1.f[j], w0.x, acc[1].x);
                acc[1].y = fmaf(av1.f[j], w0.y, acc[1].y);
                acc[2].x = fmaf(av2.f[j], w0.x, acc[2].x);
                acc[2].y = fmaf(av2.f[j], w0.y, acc[2].y);
                acc[3].x = fmaf(av3.f[j], w0.x, acc[3].x);
                acc[3].y = fmaf(av3.f[j], w0.y, acc[3].y);
            }
        }
    }
    // epilogue: 4 t-rows per thread, one matrix
    int bA = b0 + 2 * tx;
    float2 b2 = *(const float2*)&bias[bA];
    if (mz == 0) {
        const float sc = 0.05103103630798287f;  // 1/sqrt(384)
        #pragma unroll
        for (int u = 0; u < 4; ++u) {
            int t = t0 + 4 * ty + u;
            if (t < TP) {
                float2 v;
                v.x = (acc[u].x + b2.x) * sc; v.y = (acc[u].y + b2.y) * sc;
                *(float2*)&zk[t * H + bA] = v;
            }
        }
    } else if (mz == 1) {
        #pragma unroll
        for (int u = 0; u < 4; ++u) {
            int t = t0 + 4 * ty + u;
            if (t < TP) {
                float2 v;
                v.x = acc[u].x + b2.x; v.y = acc[u].y + b2.y;
                *(float2*)&ai[t * H + bA] = v;
            }
        }
    } else {
        float2 lsum = {0.f, 0.f};
        #pragma unroll
        for (int u = 0; u < 4; ++u) {
            int t = t0 + 4 * ty + u;
            if (t < TP) {
                float2 l2;
                l2.x = logsig(acc[u].x + b2.x);
                l2.y = logsig(acc[u].y + b2.y);
                *(float2*)&lf[t * H + bA] = l2;
                lsum.x += l2.x; lsum.y += l2.y;
            }
        }
        // per-8t chunk sums: ty pair (2c, 2c+1) covers chunk c
        *(float2*)&csred[ty][2 * tx] = lsum;
        __syncthreads();
        int cl = tid >> 6;       // 0..3 local chunk
        int bb = tid & 63;
        int c = blockIdx.x * 4 + cl;
        if (c < NCS)
            cs[c * H + b0 + bb] = csred[2 * cl][bb] + csred[2 * cl + 1][bb];
    }
}

// ---------- D3: reverse exclusive scan over 257 chunk sums, grid 6x64 ----------
__global__ __launch_bounds__(64) void k3b_scan(const float* __restrict__ cs,
                                               float* __restrict__ co) {
    int b = blockIdx.x * 64 + threadIdx.x;
    float L = 0.0f;
    #pragma unroll 16
    for (int c = NCS - 1; c >= 0; --c) {
        co[c * H + b] = L;
        L += cs[c * H + b];
    }
}

// ---------- D4: fused w -> g -> atomic (z, G). grid NC3 x 384, chunk 8 t ----------
// No fence/ticket epilogue (R5/R6: device-scope threadfence storms cost ~90us).
// Chunk-8 (R10: chunk-4 split regressed +6us).
__global__ __launch_bounds__(384) void k3_fused(
    const float* __restrict__ ai, const float* __restrict__ lf,
    const float* __restrict__ zk, const float* __restrict__ co,
    const float* __restrict__ q, const float* __restrict__ xp,
    float* __restrict__ zf, float* __restrict__ Gf) {
    __shared__ float zred[6][256];
    __shared__ float gred[6];
    int tid = threadIdx.x;
    int w = tid >> 6, lane = tid & 63;
    int c = blockIdx.x, ts = c * 8;
    float co0 = co[c * H + tid];
    float qb = q[tid];
    float aiv[8], lfv[8], zkv[8];
    float4 xv[8];
    if (ts + 8 <= TP) {
        #pragma unroll
        for (int u = 0; u < 8; ++u) {
            int idx = (ts + u) * H + tid;
            aiv[u] = ai[idx]; lfv[u] = lf[idx]; zkv[u] = zk[idx];
            xv[u] = *(const float4*)&xp[(ts + u) * 256 + lane * 4];
        }
    } else {
        #pragma unroll
        for (int u = 0; u < 8; ++u) {
            if (ts + u < TP) {
                int idx = (ts + u) * H + tid;
                aiv[u] = ai[idx]; lfv[u] = lf[idx]; zkv[u] = zk[idx];
                xv[u] = *(const float4*)&xp[(ts + u) * 256 + lane * 4];
            } else {
                aiv[u] = -1e30f; lfv[u] = 0.f; zkv[u] = 0.f;
                xv[u].x = xv[u].y = xv[u].z = xv[u].w = 0.f;
            }
        }
    }
    float S = 0.f, gsum = 0.f;
    float z0 = 0.f, z1 = 0.f, z2 = 0.f, z3 = 0.f;
    #pragma unroll
    for (int u = 7; u >= 0; --u) {
        float wv = __expf(aiv[u] + co0 + S) * zkv[u] * qb;
        S += lfv[u];
        float s = wv;
        s += __shfl_xor(s, 1, 64);
        s += __shfl_xor(s, 2, 64);
        s += __shfl_xor(s, 4, 64);
        s += __shfl_xor(s, 8, 64);
        s += __shfl_xor(s, 16, 64);
        s += __shfl_xor(s, 32, 64);
        gsum += s;
        z0 = fmaf(s, xv[u].x, z0);
        z1 = fmaf(s, xv[u].y, z1);
        z2 = fmaf(s, xv[u].z, z2);
        z3 = fmaf(s, xv[u].w, z3);
    }
    zred[w][lane * 4 + 0] = z0;
    zred[w][lane * 4 + 1] = z1;
    zred[w][lane * 4 + 2] = z2;
    zred[w][lane * 4 + 3] = z3;
    if (lane == 0) gred[w] = gsum;
    __syncthreads();
    if (tid < 256) {
        float s = zred[0][tid] + zred[1][tid] + zred[2][tid]
                + zred[3][tid] + zred[4][tid] + zred[5][tid];
        atomicAdd(&zf[tid], s);
    }
    if (tid == 0)
        atomicAdd(Gf, gred[0] + gred[1] + gred[2] + gred[3] + gred[4] + gred[5]);
}

// ---------- D5: wave-per-row GEMV finalize, grid 96 ----------
__global__ __launch_bounds__(256) void k6_out(const float* __restrict__ zf,
        const float* __restrict__ Gf,
        const float* __restrict__ Wv, const float* __restrict__ bv,
        const float* __restrict__ o, float* __restrict__ out) {
    int tid = threadIdx.x;
    int lane = tid & 63;
    int row = blockIdx.x * 4 + (tid >> 6);
    float Gv = Gf[0];
    float4 zv = *(const float4*)&zf[lane * 4];
    float4 wv = *(const float4*)&Wv[row * 256 + lane * 4];
    float acc = fmaf(zv.x, wv.x, fmaf(zv.y, wv.y, fmaf(zv.z, wv.z, zv.w * wv.w)));
    #pragma unroll
    for (int off = 32; off; off >>= 1) acc += __shfl_down(acc, off, 64);
    if (lane == 0)
        out[row] = o[row] * (acc + bv[row] * Gv) / fmaxf(fabsf(Gv), 1.0f);
}

extern "C" void kernel_launch(void* const* d_in, const int* in_sizes, int n_in,
                              void* d_out, int out_size, void* d_ws, size_t ws_size,
                              hipStream_t stream) {
    const float* x  = (const float*)d_in[0];
    const float* Wq = (const float*)d_in[1];  const float* bq = (const float*)d_in[2];
    const float* Wk = (const float*)d_in[3];  const float* bk = (const float*)d_in[4];
    const float* Wv = (const float*)d_in[5];  const float* bv = (const float*)d_in[6];
    const float* Wi = (const float*)d_in[7];  const float* bi = (const float*)d_in[8];
    const float* Wf = (const float*)d_in[9];  const float* bf = (const float*)d_in[10];
    const float* Wo = (const float*)d_in[11]; const float* bo = (const float*)d_in[12];
    const float* cw = (const float*)d_in[13]; const float* cb = (const float*)d_in[14];
    float* out = (float*)d_out;

    float* ws = (float*)d_ws;
    float* xp  = ws;                       // TP*F   = 525056
    float* zk  = xp  + TP * F;             // TP*H   = 787584
    float* ai  = zk  + TP * H;             // TP*H
    float* lf  = ai  + TP * H;             // TP*H
    float* cs  = lf  + TP * H;             // NCS*H  = 98688
    float* co  = cs  + NCS * H;            // NCS*H
    float* qv  = co  + NCS * H;            // H
    float* ov  = qv  + H;                  // H
    float* zf  = ov  + H;                  // F (z accumulator)
    float* Gf  = zf  + F;                  // 1 (zf+256)

    k1_front<<<610, 256, 0, stream>>>(x, cw, cb, Wq, bq, Wo, bo, xp, qv, ov, zf);
    k2_proj<<<dim3(NT2, 6, 3), 256, 0, stream>>>(xp, Wk, bk, Wi, bi, Wf, bf, zk, ai, lf, cs);
    k3b_scan<<<6, 64, 0, stream>>>(cs, co);
    k3_fused<<<NC3, 384, 0, stream>>>(ai, lf, zk, co, qv, xp, zf, Gf);
    k6_out<<<96, 256, 0, stream>>>(zf, Gf, Wv, bv, ov, out);
}